// Round 2
// baseline (318.183 us; speedup 1.0000x reference)
//
#include <hip/hip_runtime.h>

// Problem constants (static in the reference: SIZES[g] = 256 + 16*g, B=16)
#define IN_DIM   16
#define HID      64
#define OUT      32
#define NGRAPH   16
#define N_TOT    6016
#define N_PAIRS  2349056
#define TOTAL_F4 (N_PAIRS * (OUT / 4))   // 18,792,448 float4 outputs

// native 4-float vector: accepted by __builtin_nontemporal_store
typedef float f32x4 __attribute__((ext_vector_type(4)));

// sum of squares 1..n
__host__ __device__ constexpr unsigned sumsq(unsigned n) {
    return n * (n + 1u) * (2u * n + 1u) / 6u;
}
// pair offset of graph g: 256*(S(g+15) - S(15)), S(15)=1240
__host__ __device__ constexpr unsigned poff_of(unsigned g) {
    return 256u * (sumsq(g + 15u) - 1240u);
}
// node-row start of graph g: sum_{k<g} (256+16k) = 8*g*(g+31)
__host__ __device__ constexpr unsigned start_of(unsigned g) {
    return (g * (g + 31u)) << 3;
}
static_assert(poff_of(3)  == 222464u,  "poff check");
static_assert(poff_of(15) == 2103040u, "poff check");
static_assert(poff_of(15) + 496u * 496u == (unsigned)N_PAIRS, "total check");
static_assert(start_of(16) == (unsigned)N_TOT, "row total check");

// ---------------------------------------------------------------------------
// Kernel A: per-node MLP  t = relu(ape @ W1 + b1) @ W2 + b2   -> T [N_TOT, 32]
// 8 nodes per block, 32 threads per node.  (~5 us, unchanged)
// ---------------------------------------------------------------------------
__global__ __launch_bounds__(256) void mlp_kernel(
    const float* __restrict__ ape, const float* __restrict__ W1,
    const float* __restrict__ b1,  const float* __restrict__ W2,
    const float* __restrict__ b2,  float* __restrict__ T)
{
    __shared__ float Hs[8][HID];       // 2 KB
    __shared__ float W2s[HID * OUT];   // 8 KB

    // Stage W2 (2048 floats) into LDS
    for (int idx = threadIdx.x; idx < HID * OUT; idx += 256)
        W2s[idx] = W2[idx];

    const int nl   = threadIdx.x >> 5;        // node-local 0..7
    const int c    = threadIdx.x & 31;        // channel 0..31
    const int node = blockIdx.x * 8 + nl;     // grid = 752 -> exactly 6016

    // Stage 1: H[k] for k = c and c+32
    float acc0 = b1[c];
    float acc1 = b1[c + 32];
    const float* a = ape + node * IN_DIM;
#pragma unroll
    for (int d = 0; d < IN_DIM; ++d) {
        const float av = a[d];
        acc0 += av * W1[d * HID + c];
        acc1 += av * W1[d * HID + c + 32];
    }
    Hs[nl][c]      = fmaxf(acc0, 0.0f);
    Hs[nl][c + 32] = fmaxf(acc1, 0.0f);
    __syncthreads();

    // Stage 2: t[c] = b2[c] + sum_k H[k] * W2[k][c]
    float t = b2[c];
#pragma unroll
    for (int k = 0; k < HID; ++k)
        t += Hs[nl][k] * W2s[k * OUT + c];
    T[node * OUT + c] = t;
}

// ---------------------------------------------------------------------------
// Kernel B (row-per-block): block r in [0, 6016) owns output row (g, i).
//   out[poff(g) + i*n + j][:] = T[start+i][:] + T[start+j][:]
// The (g, i, n, poff) decode runs ONCE PER BLOCK (was: per thread, incl. a
// runtime-divisor integer divide). Inner loop per thread is a pure
// load -> 4 fadd -> nontemporal store stream.
//   - thread layout: c4 = tid & 7 (which float4 of the 32-float row),
//                    jl = tid >> 3 (j-lane, 32 j's per iteration)
//   - t_i float4 held in a register for the whole block
//   - stores: 256 threads -> 4 KB contiguous per iteration, coalesced;
//     nontemporal since the 300 MB output is never re-read (keeps T in L2)
// ---------------------------------------------------------------------------
__global__ __launch_bounds__(256) void pair_kernel(
    const f32x4* __restrict__ T4, f32x4* __restrict__ out4)
{
    const unsigned r = blockIdx.x;            // global output row 0..6015

    // decode graph id from row start boundaries (once per block)
    unsigned g = 0;
#pragma unroll
    for (unsigned k = 1; k < NGRAPH; ++k)
        g += (r >= start_of(k)) ? 1u : 0u;

    const unsigned start = start_of(g);       // first node row of graph g
    const unsigned n     = 256u + (g << 4);   // nodes in graph g
    const unsigned i     = r - start;         // local row index
    const unsigned poffg = poff_of(g);        // pair offset of graph g

    const unsigned c4 = threadIdx.x & 7u;     // float4 column 0..7
    const unsigned jl = threadIdx.x >> 3;     // j lane 0..31

    // t_i fragment for this thread's column (same for all j)
    const f32x4 ti = T4[r * 8u + c4];

    // all indices < 18,792,448 -> 32-bit arithmetic throughout
    const unsigned obase = (poffg + i * n) * 8u;

    const f32x4* __restrict__ pj = T4   + (start + jl) * 8u + c4;
    f32x4*       __restrict__ po = out4 + obase + jl * 8u + c4;

    for (unsigned j = jl; j < n; j += 32u, pj += 256u, po += 256u) {
        const f32x4 tj = *pj;
        __builtin_nontemporal_store(ti + tj, po);
    }
}

extern "C" void kernel_launch(void* const* d_in, const int* in_sizes, int n_in,
                              void* d_out, int out_size, void* d_ws, size_t ws_size,
                              hipStream_t stream) {
    const float* ape = (const float*)d_in[0];
    const float* W1  = (const float*)d_in[1];
    const float* b1  = (const float*)d_in[2];
    const float* W2  = (const float*)d_in[3];
    const float* b2  = (const float*)d_in[4];
    // d_in[5] = batch (unused: sizes are static), d_in[6..8] = scalars

    float* T = (float*)d_ws;   // 6016*32*4 = 770 KB scratch

    mlp_kernel<<<N_TOT / 8, 256, 0, stream>>>(ape, W1, b1, W2, b2, T);
    pair_kernel<<<N_TOT, 256, 0, stream>>>((const f32x4*)T, (f32x4*)d_out);
}